// Round 13
// baseline (331.347 us; speedup 1.0000x reference)
//
#include <hip/hip_runtime.h>

// Problem constants
#define NB 16
#define NH 64
#define NW 64
#define ND 128
#define NK 4096
#define NROWS (NB * NH * NW)        // 65536
#define OUT_ELEMS (NB * ND * NH * NW)  // 8388608
// fp16 single-term fast path: score-gap error sigma ~= 0.018; margin 0.10
// ~= 5.5 sigma. Rows with 2(B1-B3) < M get full exact rescue; rows with
// only 2(B1-B2) < M get an exact 2-code pair check (true best provably in
// {i1,i2}: any other code has fast >= B3, true >= B3 - eps, and
// B1 - B3 >= M = 2 eps means it cannot win).
#define MARGIN_F 0.10f

typedef _Float16 f16x8 __attribute__((ext_vector_type(8)));
typedef float f32x4 __attribute__((ext_vector_type(4)));

__device__ __forceinline__ unsigned short f2h(float x) {
    _Float16 h = (_Float16)x;              // v_cvt_f16_f32, RNE
    return __builtin_bit_cast(unsigned short, h);
}
// Order-preserving (score,idx) packing: smaller score first, then smaller idx.
__device__ __forceinline__ unsigned long long pack_si(float s, int idx) {
    unsigned int u = __float_as_uint(s);
    unsigned int key = ((int)u < 0) ? ~u : (u | 0x80000000u);
    return ((unsigned long long)key << 32) | (unsigned int)idx;
}

// ---------------------------------------------------------------------------
// Kernel 1: emb prep — enorm (fp32 exact) + fp16 codebook e_h stored in a
// SWIZZLED layout: ushort index = code*128 + (dim ^ ((code&7)<<3)).
// global_load_lds copies tiles verbatim (cannot scatter), so the LDS bank
// swizzle is pre-baked into the global layout; reads apply the same XOR.
// ---------------------------------------------------------------------------
__global__ void emb_prep_kernel(const float* __restrict__ emb,
                                float* __restrict__ enorm,
                                unsigned short* __restrict__ e_h) {
    int wave = (blockIdx.x * blockDim.x + threadIdx.x) >> 6;
    int lane = threadIdx.x & 63;
    if (wave >= NK) return;
    const float* e = emb + (size_t)wave * ND;
    float a = e[lane];
    float b = e[lane + 64];
    const int m = (wave & 7) << 3;
    e_h[(size_t)wave * ND + (lane ^ m)] = f2h(a);
    e_h[(size_t)wave * ND + ((lane + 64) ^ m)] = f2h(b);
    float s = a * a + b * b;
#pragma unroll
    for (int off = 32; off > 0; off >>= 1) s += __shfl_down(s, off, 64);
    if (lane == 0) enorm[wave] = s;
}

// ---------------------------------------------------------------------------
// Kernel 2: MFMA argmin (R12). R11 + top-3 score / top-2 index tracking so
// the expensive full rescue shrinks to rows with THREE codes within margin
// (~tens), while 2-close rows go to the cheap exact pair check.
// Max-form q = z.e - 0.5*en (acc-init fold, R11); argmin s == argmax q.
// ---------------------------------------------------------------------------
#define ZST 136   // z staging row stride in ushort (272 B)

__global__ void
__attribute__((amdgpu_flat_work_group_size(256, 256)))
mfma_argmin_kernel(const float* __restrict__ z,
                   const unsigned short* __restrict__ e_h,
                   const float* __restrict__ enorm,
                   int* __restrict__ idx_out,
                   int* __restrict__ rcount,
                   int* __restrict__ rlist,
                   unsigned long long* __restrict__ rpart,
                   int* __restrict__ pcount,
                   int2* __restrict__ plist) {
    // ubuf: first used as z-staging (ZST layout), then reused as the
    // double-buffered code tile: btile[b] = &ubuf[b*8192].
    __shared__ alignas(16) unsigned short ubuf[2 * 64 * ND];   // 32768 B
    __shared__ float redb1[2 * 64];
    __shared__ float redb2[2 * 64];
    __shared__ float redb3[2 * 64];
    __shared__ int   redi1[2 * 64];
    __shared__ int   redi2[2 * 64];

    const int bid = blockIdx.x;
    const int rowbase = bid * 64;
    const int t = threadIdx.x;
    const int lane = t & 63;
    const int wid = __builtin_amdgcn_readfirstlane(t >> 6);

    // ---- stage z rows (fp32 -> fp16) into ubuf (ZST layout) ----
    const float4* zg = (const float4*)(z + (size_t)rowbase * ND);
#pragma unroll
    for (int q = 0; q < 8; q++) {
        int i = t + 256 * q;               // 0..2047
        float4 v = zg[i];
        int r = i >> 5;
        int c4 = (i & 31) << 2;
        ushort4 hv = make_ushort4(f2h(v.x), f2h(v.y), f2h(v.z), f2h(v.w));
        *(ushort4*)&ubuf[r * ZST + c4] = hv;
    }
    __syncthreads();

    const int quad = lane >> 4;
    const int c = lane & 15;
    const int rh = wid >> 1;               // row half (rows rh*32..rh*32+31)
    const int ch = wid & 1;                // code half within each tile

    // ---- A-fragments -> registers (once; 8 frags = 32 VGPRs) ----
    f16x8 ar[2][4];
#pragma unroll
    for (int mi = 0; mi < 2; mi++)
#pragma unroll
        for (int kk = 0; kk < 4; kk++)
            ar[mi][kk] = *(const f16x8*)&ubuf[(rh * 32 + mi * 16 + c) * ZST + quad * 8 + kk * 32];
    __syncthreads();   // all frag reads done; ubuf may now be overwritten

    // ---- prologue: stage code-tile 0 + load en(0) into regs ----
#pragma unroll
    for (int j = 0; j < 4; j++) {
        int seg = (wid << 2) + j;
        __builtin_amdgcn_global_load_lds(
            (const unsigned int*)(e_h + seg * 512 + lane * 8),
            (unsigned int*)&ubuf[seg * 512], 16, 0, 0);
    }
    float en0 = enorm[ch * 32 + c];
    float en1 = enorm[ch * 32 + 16 + c];
    __syncthreads();   // drain tile-0 (+ en(0) completes under the drain)

    const int bswz = (c & 7) << 3;         // read-side swizzle (matches prep)
    const int bbase0 = (ch * 32 + c) * ND;

    // max-form top-3 scores (b1>=b2>=b3) + top-2 indices
    float b1[2][4], b2[2][4], b3[2][4];
    int i1[2][4], i2[2][4];
#pragma unroll
    for (int mi = 0; mi < 2; mi++)
#pragma unroll
        for (int r = 0; r < 4; r++) {
            b1[mi][r] = -3.4e38f; b2[mi][r] = -3.4e38f; b3[mi][r] = -3.4e38f;
            i1[mi][r] = 0; i2[mi][r] = 0;
        }

    for (int ts = 0; ts < NK / 64; ts++) {
        const int cur = ts & 1;
        const int curoff = cur << 13;      // cur * 8192 ushorts

        // pipeline: issue next step's en loads + tile stage FIRST; both are
        // consumed only AFTER the end-of-step drain, so their latency hides
        // under this step's compute regardless of vmcnt retirement order.
        float nen0 = 0.f, nen1 = 0.f;
        if (ts < NK / 64 - 1) {
            nen0 = enorm[(ts + 1) * 64 + ch * 32 + c];
            nen1 = enorm[(ts + 1) * 64 + ch * 32 + 16 + c];
            const unsigned short* gt = e_h + (size_t)(ts + 1) * (64 * ND);
#pragma unroll
            for (int j = 0; j < 4; j++) {
                int seg = (wid << 2) + j;
                __builtin_amdgcn_global_load_lds(
                    (const unsigned int*)(gt + seg * 512 + lane * 8),
                    (unsigned int*)&ubuf[(curoff ^ 8192) + seg * 512], 16, 0, 0);
            }
        }

        // acc init = -0.5*en  ->  MFMA output q = z.e - 0.5*en
        const float h0 = -0.5f * en0;
        const float h1 = -0.5f * en1;
        f32x4 acc[2][2];
#pragma unroll
        for (int mi = 0; mi < 2; mi++) {
            acc[mi][0] = (f32x4){h0, h0, h0, h0};
            acc[mi][1] = (f32x4){h1, h1, h1, h1};
        }

#pragma unroll
        for (int kk = 0; kk < 4; kk++) {
            const int doff = (quad * 8 + kk * 32) ^ bswz;
            f16x8 bv0 = *(const f16x8*)&ubuf[curoff + bbase0 + doff];
            f16x8 bv1 = *(const f16x8*)&ubuf[curoff + bbase0 + 16 * ND + doff];
            acc[0][0] = __builtin_amdgcn_mfma_f32_16x16x32_f16(ar[0][kk], bv0, acc[0][0], 0, 0, 0);
            acc[0][1] = __builtin_amdgcn_mfma_f32_16x16x32_f16(ar[0][kk], bv1, acc[0][1], 0, 0, 0);
            acc[1][0] = __builtin_amdgcn_mfma_f32_16x16x32_f16(ar[1][kk], bv0, acc[1][0], 0, 0, 0);
            acc[1][1] = __builtin_amdgcn_mfma_f32_16x16x32_f16(ar[1][kk], bv1, acc[1][1], 0, 0, 0);
        }

#pragma unroll
        for (int ni = 0; ni < 2; ni++) {
            const int n = ts * 64 + ch * 32 + ni * 16 + c;
#pragma unroll
            for (int mi = 0; mi < 2; mi++)
#pragma unroll
                for (int r = 0; r < 4; r++) {
                    float q = acc[mi][ni][r];
                    // top-3 insert (uses OLD b1/b2 for the index selects)
                    b3[mi][r] = fmaxf(b3[mi][r], fminf(b2[mi][r], q));
                    i2[mi][r] = (q > b1[mi][r]) ? i1[mi][r]
                              : ((q > b2[mi][r]) ? n : i2[mi][r]);
                    b2[mi][r] = fmaxf(b2[mi][r], fminf(b1[mi][r], q));
                    i1[mi][r] = (q > b1[mi][r]) ? n : i1[mi][r];
                    b1[mi][r] = fmaxf(b1[mi][r], q);
                }
        }

        // one barrier per step: next tile staged for everyone, and everyone
        // is done reading cur before it is overwritten next step.
        __syncthreads();
        en0 = nen0;
        en1 = nen1;
    }

    // ---- reduce over the 16 c-lanes within each wave (top-3 merge) ----
    // Merge rule for two descending triples A,B (loser-side third can never
    // place): winner-side second/third (w2,w3), loser first (l1), loser
    // second (v2): m2 = max(l1,w2); m3 = max(min(l1,w2), w3, v2).
#pragma unroll
    for (int off = 1; off < 16; off <<= 1) {
#pragma unroll
        for (int mi = 0; mi < 2; mi++)
#pragma unroll
            for (int r = 0; r < 4; r++) {
                float ob1 = __shfl_xor(b1[mi][r], off, 64);
                float ob2 = __shfl_xor(b2[mi][r], off, 64);
                float ob3 = __shfl_xor(b3[mi][r], off, 64);
                int oi1 = __shfl_xor(i1[mi][r], off, 64);
                int oi2 = __shfl_xor(i2[mi][r], off, 64);
                bool f = ob1 > b1[mi][r];
                float w2 = f ? ob2 : b2[mi][r];
                float w3 = f ? ob3 : b3[mi][r];
                float l1 = f ? b1[mi][r] : ob1;
                float v2 = f ? b2[mi][r] : ob2;
                int wi2 = f ? oi2 : i2[mi][r];
                int li1 = f ? i1[mi][r] : oi1;
                i1[mi][r] = f ? oi1 : i1[mi][r];
                b1[mi][r] = fmaxf(b1[mi][r], ob1);
                bool g = l1 > w2;
                i2[mi][r] = g ? li1 : wi2;
                b2[mi][r] = fmaxf(l1, w2);
                b3[mi][r] = fmaxf(fmaxf(fminf(l1, w2), w3), v2);
            }
    }

    // ---- 2-way merge across code-halves ----
    if (c == 0) {
#pragma unroll
        for (int mi = 0; mi < 2; mi++)
#pragma unroll
            for (int r = 0; r < 4; r++) {
                int rowl = rh * 32 + mi * 16 + quad * 4 + r;
                redb1[ch * 64 + rowl] = b1[mi][r];
                redb2[ch * 64 + rowl] = b2[mi][r];
                redb3[ch * 64 + rowl] = b3[mi][r];
                redi1[ch * 64 + rowl] = i1[mi][r];
                redi2[ch * 64 + rowl] = i2[mi][r];
            }
    }
    __syncthreads();

    if (t < 64) {
        float B1 = redb1[t], B2 = redb2[t], B3 = redb3[t];
        int I1 = redi1[t], I2 = redi2[t];
        float ob1 = redb1[64 + t], ob2 = redb2[64 + t], ob3 = redb3[64 + t];
        int oi1 = redi1[64 + t], oi2 = redi2[64 + t];
        bool f = ob1 > B1;
        float w2 = f ? ob2 : B2;
        float w3 = f ? ob3 : B3;
        float l1 = f ? B1 : ob1;
        float v2 = f ? B2 : ob2;
        int wi2 = f ? oi2 : I2;
        int li1 = f ? I1 : oi1;
        I1 = f ? oi1 : I1;
        B1 = fmaxf(B1, ob1);
        bool g = l1 > w2;
        I2 = g ? li1 : wi2;
        B2 = fmaxf(l1, w2);
        B3 = fmaxf(fmaxf(fminf(l1, w2), w3), v2);

        idx_out[rowbase + t] = I1;
        // score gaps (distance domain = 2x the q domain)
        if (2.0f * (B1 - B3) < MARGIN_F) {
            // three codes within margin -> full exact rescue
            rpart[rowbase + t] = ~0ull;
            int p = atomicAdd(rcount, 1);
            rlist[p] = rowbase + t;
        } else if (2.0f * (B1 - B2) < MARGIN_F) {
            // only top-2 ambiguous -> exact pair check
            int p = atomicAdd(pcount, 1);
            plist[p] = make_int2(rowbase + t, I2);
        }
    }
}

// ---------------------------------------------------------------------------
// Kernel 3: exact fp32 rescue (unchanged; now only 3-close rows, ~tens).
// ---------------------------------------------------------------------------
#define RR 4        // rows per group
#define SC 512      // codes per slice
#define CH 64       // codes per staged chunk

__global__ void __launch_bounds__(256, 2)
rescue_kernel(const float* __restrict__ z,
              const float* __restrict__ emb,
              const float* __restrict__ enorm,
              const int* __restrict__ rcount,
              const int* __restrict__ rlist,
              unsigned long long* __restrict__ rpart) {
    __shared__ float2 ze[64 * RR];       // ze[d2*RR + r]
    __shared__ float2 es[64 * 65];       // es[d2*65 + code]
    __shared__ int ids[RR];

    const int t = threadIdx.x;
    const int cnt = *rcount;
    if (cnt == 0) return;
    const int ngrp = (cnt + RR - 1) / RR;
    const int nwork = ngrp * 8;

    const int r = t >> 6;                // 0..3 (== wave id)
    const int cl = t & 63;

    for (int g = blockIdx.x; g < nwork; g += gridDim.x) {
        const int gi = g >> 3;
        const int slice = g & 7;

        if (t < RR) {
            int j = gi * RR + t;
            ids[t] = rlist[j < cnt ? j : cnt - 1];
        }
        __syncthreads();                 // publish ids
        const int row = ids[r];
        ze[cl * RR + r] = ((const float2*)(z + (size_t)row * ND))[cl];  // coalesced

        unsigned long long bestp = ~0ull;
        const int kbase = slice * SC;

        for (int ch2 = 0; ch2 < SC / CH; ch2++) {
            __syncthreads();             // es safe to overwrite (also publishes ze on ch2==0)
#pragma unroll
            for (int q = 0; q < 16; q++) {
                int i = t + 256 * q;     // 0..4095
                int code = i >> 6;
                int d2 = i & 63;
                float2 v = ((const float2*)(emb + (size_t)(kbase + ch2 * CH + code) * ND))[d2];
                es[d2 * 65 + code] = v;
            }
            __syncthreads();

            int k = kbase + ch2 * CH + cl;
            float a0 = 0.f, a1 = 0.f, a2 = 0.f, a3 = 0.f;
#pragma unroll
            for (int d2 = 0; d2 < 64; d2 += 2) {
                float2 zv0 = ze[d2 * RR + r];            // wave-uniform
                float2 ev0 = es[d2 * 65 + cl];           // conflict-free
                float2 zv1 = ze[(d2 + 1) * RR + r];
                float2 ev1 = es[(d2 + 1) * 65 + cl];
                a0 = fmaf(zv0.x, ev0.x, a0);
                a1 = fmaf(zv0.y, ev0.y, a1);
                a2 = fmaf(zv1.x, ev1.x, a2);
                a3 = fmaf(zv1.y, ev1.y, a3);
            }
            float s = fmaf(-2.0f, (a0 + a1) + (a2 + a3), enorm[k]);
            unsigned long long p = pack_si(s, k);
            bestp = (p < bestp) ? p : bestp;
        }

        // wave-reduce min (all lanes in this wave share the same row)
#pragma unroll
        for (int off = 32; off > 0; off >>= 1) {
            unsigned long long o = __shfl_down(bestp, off, 64);
            bestp = (o < bestp) ? o : bestp;
        }
        if (cl == 0) atomicMin(&rpart[row], bestp);
        __syncthreads();                 // protect ids/ze before next g
    }
}

// ---------------------------------------------------------------------------
// Kernel 4: rescue finalize — unpack winning idx per rescue row.
// ---------------------------------------------------------------------------
__global__ void rescue_fin_kernel(const int* __restrict__ rcount,
                                  const int* __restrict__ rlist,
                                  const unsigned long long* __restrict__ rpart,
                                  int* __restrict__ idx_out) {
    const int cnt = *rcount;
    for (int i = blockIdx.x * blockDim.x + threadIdx.x; i < cnt;
         i += gridDim.x * blockDim.x) {
        int row = rlist[i];
        idx_out[row] = (int)(rpart[row] & 0xffffffffull);
    }
}

// ---------------------------------------------------------------------------
// Kernel 4b: exact pair check — one wave per ambiguous-top-2 row.
// True best is provably in {i1, i2}; compute both distances exactly in fp32
// and pick (pack_si tie-break matches the rescue path's ordering).
// ---------------------------------------------------------------------------
__global__ void pair_kernel(const float* __restrict__ z,
                            const float* __restrict__ emb,
                            const float* __restrict__ enorm,
                            const int* __restrict__ pcount,
                            const int2* __restrict__ plist,
                            int* __restrict__ idx_out) {
    const int cnt = *pcount;
    const int lane = threadIdx.x & 63;
    const int gw = (blockIdx.x * blockDim.x + threadIdx.x) >> 6;
    const int nw = (gridDim.x * blockDim.x) >> 6;
    for (int i = gw; i < cnt; i += nw) {
        int2 p = plist[i];
        const int row = p.x;
        const int j2 = p.y;
        const int j1 = idx_out[row];
        float2 zv = ((const float2*)(z + (size_t)row * ND))[lane];
        float2 e1 = ((const float2*)(emb + (size_t)j1 * ND))[lane];
        float2 e2 = ((const float2*)(emb + (size_t)j2 * ND))[lane];
        float d1 = zv.x * e1.x + zv.y * e1.y;
        float d2 = zv.x * e2.x + zv.y * e2.y;
#pragma unroll
        for (int off = 32; off > 0; off >>= 1) {
            d1 += __shfl_down(d1, off, 64);
            d2 += __shfl_down(d2, off, 64);
        }
        if (lane == 0) {
            float s1 = fmaf(-2.0f, d1, enorm[j1]);
            float s2 = fmaf(-2.0f, d2, enorm[j2]);
            unsigned long long p1 = pack_si(s1, j1);
            unsigned long long p2 = pack_si(s2, j2);
            idx_out[row] = (int)(((p2 < p1) ? p2 : p1) & 0xffffffffull);
        }
    }
}

// ---------------------------------------------------------------------------
// Kernel 5: gather + loss partial + transposed write (unchanged).
// ---------------------------------------------------------------------------
__global__ void out_kernel(const float* __restrict__ z,
                           const float* __restrict__ emb,
                           const int* __restrict__ idx,
                           float* __restrict__ out,
                           float* __restrict__ losspart) {
    __shared__ float zq[64 * 129];
    __shared__ int ids[64];
    __shared__ float redl[4];

    const int bid = blockIdx.x;
    const int b = bid >> 6;
    const int h = bid & 63;
    const int rowbase = bid * 64;
    const int t = threadIdx.x;

    if (t < 64) ids[t] = idx[rowbase + t];
    __syncthreads();

    const int d = t & 127;
    const int w0 = t >> 7;
    float lsum = 0.f;
#pragma unroll
    for (int wq = 0; wq < 32; wq++) {
        int w = w0 + 2 * wq;
        float e = emb[(size_t)ids[w] * ND + d];
        float zv = z[((size_t)(rowbase + w)) * ND + d];
        float df = e - zv;
        lsum = fmaf(df, df, lsum);
        zq[w * 129 + d] = e;
    }
#pragma unroll
    for (int off = 32; off > 0; off >>= 1) lsum += __shfl_down(lsum, off, 64);
    if ((t & 63) == 0) redl[t >> 6] = lsum;
    __syncthreads();
    if (t == 0) losspart[bid] = redl[0] + redl[1] + redl[2] + redl[3];

    const int w = t & 63;
    const int dq = t >> 6;
#pragma unroll
    for (int dd0 = 0; dd0 < 32; dd0++) {
        int dd = dq + 4 * dd0;
        out[(((size_t)b * ND + dd) * NH + h) * NW + w] = zq[w * 129 + dd];
    }
}

// ---------------------------------------------------------------------------
// Kernel 6: final loss reduce
// ---------------------------------------------------------------------------
__global__ void loss_kernel(const float* __restrict__ losspart,
                            float* __restrict__ out) {
    __shared__ float redl[4];
    const int t = threadIdx.x;
    float s = 0.f;
#pragma unroll
    for (int i = 0; i < 4; i++) s += losspart[t + 256 * i];
#pragma unroll
    for (int off = 32; off > 0; off >>= 1) s += __shfl_down(s, off, 64);
    if ((t & 63) == 0) redl[t >> 6] = s;
    __syncthreads();
    if (t == 0) {
        float total = redl[0] + redl[1] + redl[2] + redl[3];
        out[OUT_ELEMS] = 1.25f * total / (float)OUT_ELEMS;
    }
}

// ---------------------------------------------------------------------------
extern "C" void kernel_launch(void* const* d_in, const int* in_sizes, int n_in,
                              void* d_out, int out_size, void* d_ws, size_t ws_size,
                              hipStream_t stream) {
    const float* z = (const float*)d_in[0];      // [16,64,64,128] fp32
    const float* emb = (const float*)d_in[1];    // [4096,128] fp32
    float* out = (float*)d_out;                  // 8388608 + 1 fp32

    char* ws = (char*)d_ws;
    int* ws_idx = (int*)ws;                                         // 256 KB
    float* ws_enorm = (float*)(ws + (256 << 10));                   // 16 KB
    float* ws_losspart = (float*)(ws + (272 << 10));                // 4 KB
    int* ws_rcount = (int*)(ws + (276 << 10));                      // rcount + pcount (8 B)
    int* ws_pcount = ws_rcount + 1;
    int* ws_rlist = (int*)(ws + (277 << 10));                       // 256 KB
    unsigned short* ws_eh = (unsigned short*)(ws + (533 << 10));    // 1 MB
    unsigned long long* ws_rpart = (unsigned long long*)(ws + (1557 << 10)); // 512 KB
    int2* ws_plist = (int2*)(ws + (2069 << 10));                    // 512 KB

    hipMemsetAsync(ws_rcount, 0, 2 * sizeof(int), stream);
    emb_prep_kernel<<<NK / 4, 256, 0, stream>>>(emb, ws_enorm, ws_eh);
    mfma_argmin_kernel<<<NROWS / 64, 256, 0, stream>>>(z, ws_eh, ws_enorm,
                                                       ws_idx, ws_rcount,
                                                       ws_rlist, ws_rpart,
                                                       ws_pcount, ws_plist);
    rescue_kernel<<<2048, 256, 0, stream>>>(z, emb, ws_enorm, ws_rcount,
                                            ws_rlist, ws_rpart);
    pair_kernel<<<256, 256, 0, stream>>>(z, emb, ws_enorm, ws_pcount,
                                         ws_plist, ws_idx);
    rescue_fin_kernel<<<64, 256, 0, stream>>>(ws_rcount, ws_rlist, ws_rpart,
                                              ws_idx);
    out_kernel<<<NB * NH, 256, 0, stream>>>(z, emb, ws_idx, out, ws_losspart);
    loss_kernel<<<1, 256, 0, stream>>>(ws_losspart, out);
}

// Round 14
// 325.896 us; speedup vs baseline: 1.0167x; 1.0167x over previous
//
#include <hip/hip_runtime.h>

// Problem constants
#define NB 16
#define NH 64
#define NW 64
#define ND 128
#define NK 4096
#define NROWS (NB * NH * NW)        // 65536
#define OUT_ELEMS (NB * ND * NH * NW)  // 8388608
// fp16 single-term fast path: score-gap error sigma ~= 0.02; margin 0.10
// ~= 5 sigma. Exact-fp32 rescue handles everything below the margin.
// R13 lesson: top-3+index tracking in the hot loop costs 2x argmin (VALU
// issue-bound at ~5 ops/score budget) — rescue stays full-scan, optimized
// structurally instead.
#define MARGIN_F 0.10f

typedef _Float16 f16x8 __attribute__((ext_vector_type(8)));
typedef float f32x4 __attribute__((ext_vector_type(4)));

__device__ __forceinline__ unsigned short f2h(float x) {
    _Float16 h = (_Float16)x;              // v_cvt_f16_f32, RNE
    return __builtin_bit_cast(unsigned short, h);
}
// Order-preserving (score,idx) packing: smaller score first, then smaller idx.
__device__ __forceinline__ unsigned long long pack_si(float s, int idx) {
    unsigned int u = __float_as_uint(s);
    unsigned int key = ((int)u < 0) ? ~u : (u | 0x80000000u);
    return ((unsigned long long)key << 32) | (unsigned int)idx;
}

// ---------------------------------------------------------------------------
// Kernel 1: emb prep — enorm (fp32 exact) + fp16 codebook e_h stored in a
// SWIZZLED layout: ushort index = code*128 + (dim ^ ((code&7)<<3)).
// global_load_lds copies tiles verbatim (cannot scatter), so the LDS bank
// swizzle is pre-baked into the global layout; reads apply the same XOR.
// ---------------------------------------------------------------------------
__global__ void emb_prep_kernel(const float* __restrict__ emb,
                                float* __restrict__ enorm,
                                unsigned short* __restrict__ e_h) {
    int wave = (blockIdx.x * blockDim.x + threadIdx.x) >> 6;
    int lane = threadIdx.x & 63;
    if (wave >= NK) return;
    const float* e = emb + (size_t)wave * ND;
    float a = e[lane];
    float b = e[lane + 64];
    const int m = (wave & 7) << 3;
    e_h[(size_t)wave * ND + (lane ^ m)] = f2h(a);
    e_h[(size_t)wave * ND + ((lane + 64) ^ m)] = f2h(b);
    float s = a * a + b * b;
#pragma unroll
    for (int off = 32; off > 0; off >>= 1) s += __shfl_down(s, off, 64);
    if (lane == 0) enorm[wave] = s;
}

// ---------------------------------------------------------------------------
// Kernel 2: MFMA argmin (R11 verified version, reverted from R13's top-3).
// Max-form q = z.e - 0.5*en via acc-init fold; argmin s == argmax q;
// branch-free top-2 update (5 ops/score). 121us @ Occ 33% measured.
// ---------------------------------------------------------------------------
#define ZST 136   // z staging row stride in ushort (272 B)

__global__ void
__attribute__((amdgpu_flat_work_group_size(256, 256)))
mfma_argmin_kernel(const float* __restrict__ z,
                   const unsigned short* __restrict__ e_h,
                   const float* __restrict__ enorm,
                   int* __restrict__ idx_out,
                   int* __restrict__ rcount,
                   int* __restrict__ rlist,
                   unsigned long long* __restrict__ rpart) {
    // ubuf: first used as z-staging (ZST layout), then reused as the
    // double-buffered code tile: btile[b] = &ubuf[b*8192].
    __shared__ alignas(16) unsigned short ubuf[2 * 64 * ND];   // 32768 B
    __shared__ float redb1[2 * 64];
    __shared__ float redb2[2 * 64];
    __shared__ int   redi1[2 * 64];

    const int bid = blockIdx.x;
    const int rowbase = bid * 64;
    const int t = threadIdx.x;
    const int lane = t & 63;
    const int wid = __builtin_amdgcn_readfirstlane(t >> 6);

    // ---- stage z rows (fp32 -> fp16) into ubuf (ZST layout) ----
    const float4* zg = (const float4*)(z + (size_t)rowbase * ND);
#pragma unroll
    for (int q = 0; q < 8; q++) {
        int i = t + 256 * q;               // 0..2047
        float4 v = zg[i];
        int r = i >> 5;
        int c4 = (i & 31) << 2;
        ushort4 hv = make_ushort4(f2h(v.x), f2h(v.y), f2h(v.z), f2h(v.w));
        *(ushort4*)&ubuf[r * ZST + c4] = hv;
    }
    __syncthreads();

    const int quad = lane >> 4;
    const int c = lane & 15;
    const int rh = wid >> 1;               // row half (rows rh*32..rh*32+31)
    const int ch = wid & 1;                // code half within each tile

    // ---- A-fragments -> registers (once; 8 frags = 32 VGPRs) ----
    f16x8 ar[2][4];
#pragma unroll
    for (int mi = 0; mi < 2; mi++)
#pragma unroll
        for (int kk = 0; kk < 4; kk++)
            ar[mi][kk] = *(const f16x8*)&ubuf[(rh * 32 + mi * 16 + c) * ZST + quad * 8 + kk * 32];
    __syncthreads();   // all frag reads done; ubuf may now be overwritten

    // ---- prologue: stage code-tile 0 + load en(0) into regs ----
#pragma unroll
    for (int j = 0; j < 4; j++) {
        int seg = (wid << 2) + j;
        __builtin_amdgcn_global_load_lds(
            (const unsigned int*)(e_h + seg * 512 + lane * 8),
            (unsigned int*)&ubuf[seg * 512], 16, 0, 0);
    }
    float en0 = enorm[ch * 32 + c];
    float en1 = enorm[ch * 32 + 16 + c];
    __syncthreads();   // drain tile-0 (+ en(0) completes under the drain)

    const int bswz = (c & 7) << 3;         // read-side swizzle (matches prep)
    const int bbase0 = (ch * 32 + c) * ND;

    // max-form top-2: b1 = max q, b2 = second-max q (invariant b1 >= b2)
    float b1[2][4], b2[2][4];
    int i1[2][4];
#pragma unroll
    for (int mi = 0; mi < 2; mi++)
#pragma unroll
        for (int r = 0; r < 4; r++) { b1[mi][r] = -3.4e38f; b2[mi][r] = -3.4e38f; i1[mi][r] = 0; }

    for (int ts = 0; ts < NK / 64; ts++) {
        const int cur = ts & 1;
        const int curoff = cur << 13;      // cur * 8192 ushorts

        // pipeline: issue next step's en loads + tile stage FIRST; both are
        // consumed only AFTER the end-of-step drain, so their latency hides
        // under this step's compute regardless of vmcnt retirement order.
        float nen0 = 0.f, nen1 = 0.f;
        if (ts < NK / 64 - 1) {
            nen0 = enorm[(ts + 1) * 64 + ch * 32 + c];
            nen1 = enorm[(ts + 1) * 64 + ch * 32 + 16 + c];
            const unsigned short* gt = e_h + (size_t)(ts + 1) * (64 * ND);
#pragma unroll
            for (int j = 0; j < 4; j++) {
                int seg = (wid << 2) + j;
                __builtin_amdgcn_global_load_lds(
                    (const unsigned int*)(gt + seg * 512 + lane * 8),
                    (unsigned int*)&ubuf[(curoff ^ 8192) + seg * 512], 16, 0, 0);
            }
        }

        // acc init = -0.5*en  ->  MFMA output q = z.e - 0.5*en
        const float h0 = -0.5f * en0;
        const float h1 = -0.5f * en1;
        f32x4 acc[2][2];
#pragma unroll
        for (int mi = 0; mi < 2; mi++) {
            acc[mi][0] = (f32x4){h0, h0, h0, h0};
            acc[mi][1] = (f32x4){h1, h1, h1, h1};
        }

#pragma unroll
        for (int kk = 0; kk < 4; kk++) {
            const int doff = (quad * 8 + kk * 32) ^ bswz;
            f16x8 bv0 = *(const f16x8*)&ubuf[curoff + bbase0 + doff];
            f16x8 bv1 = *(const f16x8*)&ubuf[curoff + bbase0 + 16 * ND + doff];
            acc[0][0] = __builtin_amdgcn_mfma_f32_16x16x32_f16(ar[0][kk], bv0, acc[0][0], 0, 0, 0);
            acc[0][1] = __builtin_amdgcn_mfma_f32_16x16x32_f16(ar[0][kk], bv1, acc[0][1], 0, 0, 0);
            acc[1][0] = __builtin_amdgcn_mfma_f32_16x16x32_f16(ar[1][kk], bv0, acc[1][0], 0, 0, 0);
            acc[1][1] = __builtin_amdgcn_mfma_f32_16x16x32_f16(ar[1][kk], bv1, acc[1][1], 0, 0, 0);
        }

#pragma unroll
        for (int ni = 0; ni < 2; ni++) {
            const int n = ts * 64 + ch * 32 + ni * 16 + c;
#pragma unroll
            for (int mi = 0; mi < 2; mi++)
#pragma unroll
                for (int r = 0; r < 4; r++) {
                    float q = acc[mi][ni][r];
                    // branch-free top-2-max insert (5 VALU ops)
                    b2[mi][r] = fmaxf(b2[mi][r], fminf(b1[mi][r], q));
                    i1[mi][r] = (q > b1[mi][r]) ? n : i1[mi][r];
                    b1[mi][r] = fmaxf(b1[mi][r], q);
                }
        }

        // one barrier per step: next tile staged for everyone, and everyone
        // is done reading cur before it is overwritten next step.
        __syncthreads();
        en0 = nen0;
        en1 = nen1;
    }

    // ---- reduce over the 16 c-lanes (codes) within each wave (max-form) ----
#pragma unroll
    for (int off = 1; off < 16; off <<= 1) {
#pragma unroll
        for (int mi = 0; mi < 2; mi++)
#pragma unroll
            for (int r = 0; r < 4; r++) {
                float ob1 = __shfl_xor(b1[mi][r], off, 64);
                float ob2 = __shfl_xor(b2[mi][r], off, 64);
                int oi1 = __shfl_xor(i1[mi][r], off, 64);
                float hi = fmaxf(b1[mi][r], ob1);
                float lo = fminf(b1[mi][r], ob1);
                b2[mi][r] = fmaxf(fmaxf(b2[mi][r], ob2), lo);
                i1[mi][r] = (ob1 > b1[mi][r]) ? oi1 : i1[mi][r];
                b1[mi][r] = hi;
            }
    }

    // ---- 2-way merge across code-halves ----
    if (c == 0) {
#pragma unroll
        for (int mi = 0; mi < 2; mi++)
#pragma unroll
            for (int r = 0; r < 4; r++) {
                int rowl = rh * 32 + mi * 16 + quad * 4 + r;
                redb1[ch * 64 + rowl] = b1[mi][r];
                redb2[ch * 64 + rowl] = b2[mi][r];
                redi1[ch * 64 + rowl] = i1[mi][r];
            }
    }
    __syncthreads();

    if (t < 64) {
        float B1 = redb1[t], B2 = redb2[t];
        int I1 = redi1[t];
        float ob1 = redb1[64 + t];
        float ob2 = redb2[64 + t];
        int oi1 = redi1[64 + t];
        float hi = fmaxf(B1, ob1);
        float lo = fminf(B1, ob1);
        B2 = fmaxf(fmaxf(B2, ob2), lo);
        I1 = (ob1 > B1) ? oi1 : I1;
        B1 = hi;
        idx_out[rowbase + t] = I1;
        // score gap = 2*(B1q - B2q) in the distance domain
        if (2.0f * (B1 - B2) < MARGIN_F) {
            rpart[rowbase + t] = ~0ull;          // init for rescue atomicMin
            int p = atomicAdd(rcount, 1);
            rlist[p] = rowbase + t;
        }
    }
}

// ---------------------------------------------------------------------------
// Kernel 3: exact fp32 rescue (R14: RR 4->8, two rows per thread).
// R11 profile: 121us, VALU 31%, Occ 19%, HBM 0.4% -> ds_read-issue bound
// (4 LDS reads per 4 FMAs) + staging amortized over only 4 rows.
// Now: wave r owns rows r and r+4; each es read feeds BOTH rows (per-row
// LDS reads 2 -> 1.5); per-row staging traffic halves; ze relaid [rr][d2]
// (write: consecutive 8B per wave = conflict-free; read: wave-uniform
// broadcast). Per-row 4-partial summation identical to the verified R11
// rescue ordering.
// ---------------------------------------------------------------------------
#define RR 8        // rows per group (2 per wave)
#define SC 512      // codes per slice
#define CH 64       // codes per staged chunk

__global__ void __launch_bounds__(256, 2)
rescue_kernel(const float* __restrict__ z,
              const float* __restrict__ emb,
              const float* __restrict__ enorm,
              const int* __restrict__ rcount,
              const int* __restrict__ rlist,
              unsigned long long* __restrict__ rpart) {
    __shared__ float2 ze[RR * 64];       // ze[rr*64 + d2]
    __shared__ float2 es[64 * 65];       // es[d2*65 + code]
    __shared__ int ids[RR];

    const int t = threadIdx.x;
    const int cnt = *rcount;
    if (cnt == 0) return;
    const int ngrp = (cnt + RR - 1) / RR;
    const int nwork = ngrp * 8;

    const int r = t >> 6;                // wave id 0..3; rows r and r+4
    const int cl = t & 63;

    for (int g = blockIdx.x; g < nwork; g += gridDim.x) {
        const int gi = g >> 3;
        const int slice = g & 7;

        if (t < RR) {
            int j = gi * RR + t;
            ids[t] = rlist[j < cnt ? j : cnt - 1];
        }
        __syncthreads();                 // publish ids
        const int rowA = ids[r];
        const int rowB = ids[r + 4];
        // stage ze: 512 float2; thread stages 2 (coalesced 8B per row-chunk)
#pragma unroll
        for (int q2 = 0; q2 < 2; q2++) {
            int i = t + 256 * q2;        // 0..511
            int rr = i >> 6;
            int d2 = i & 63;
            ze[rr * 64 + d2] = ((const float2*)(z + (size_t)ids[rr] * ND))[d2];
        }

        unsigned long long bestA = ~0ull, bestB = ~0ull;
        const int kbase = slice * SC;

        for (int ch2 = 0; ch2 < SC / CH; ch2++) {
            __syncthreads();             // es safe to overwrite (also publishes ze on ch2==0)
#pragma unroll
            for (int q = 0; q < 16; q++) {
                int i = t + 256 * q;     // 0..4095
                int code = i >> 6;
                int d2 = i & 63;
                float2 v = ((const float2*)(emb + (size_t)(kbase + ch2 * CH + code) * ND))[d2];
                es[d2 * 65 + code] = v;
            }
            __syncthreads();

            int k = kbase + ch2 * CH + cl;
            float a0 = 0.f, a1 = 0.f, a2 = 0.f, a3 = 0.f;
            float c0 = 0.f, c1 = 0.f, c2 = 0.f, c3 = 0.f;
#pragma unroll
            for (int d2 = 0; d2 < 64; d2 += 2) {
                float2 ev0 = es[d2 * 65 + cl];           // conflict-free
                float2 ev1 = es[(d2 + 1) * 65 + cl];
                float2 zA0 = ze[r * 64 + d2];            // wave-uniform
                float2 zA1 = ze[r * 64 + d2 + 1];
                float2 zB0 = ze[(r + 4) * 64 + d2];
                float2 zB1 = ze[(r + 4) * 64 + d2 + 1];
                a0 = fmaf(zA0.x, ev0.x, a0);
                a1 = fmaf(zA0.y, ev0.y, a1);
                a2 = fmaf(zA1.x, ev1.x, a2);
                a3 = fmaf(zA1.y, ev1.y, a3);
                c0 = fmaf(zB0.x, ev0.x, c0);
                c1 = fmaf(zB0.y, ev0.y, c1);
                c2 = fmaf(zB1.x, ev1.x, c2);
                c3 = fmaf(zB1.y, ev1.y, c3);
            }
            float sA = fmaf(-2.0f, (a0 + a1) + (a2 + a3), enorm[k]);
            float sB = fmaf(-2.0f, (c0 + c1) + (c2 + c3), enorm[k]);
            unsigned long long pA = pack_si(sA, k);
            unsigned long long pB = pack_si(sB, k);
            bestA = (pA < bestA) ? pA : bestA;
            bestB = (pB < bestB) ? pB : bestB;
        }

        // wave-reduce min for both rows
#pragma unroll
        for (int off = 32; off > 0; off >>= 1) {
            unsigned long long oA = __shfl_down(bestA, off, 64);
            unsigned long long oB = __shfl_down(bestB, off, 64);
            bestA = (oA < bestA) ? oA : bestA;
            bestB = (oB < bestB) ? oB : bestB;
        }
        if (cl == 0) {
            atomicMin(&rpart[rowA], bestA);
            atomicMin(&rpart[rowB], bestB);
        }
        __syncthreads();                 // protect ids/ze before next g
    }
}

// ---------------------------------------------------------------------------
// Kernel 4: rescue finalize — unpack winning idx per rescue row.
// ---------------------------------------------------------------------------
__global__ void rescue_fin_kernel(const int* __restrict__ rcount,
                                  const int* __restrict__ rlist,
                                  const unsigned long long* __restrict__ rpart,
                                  int* __restrict__ idx_out) {
    const int cnt = *rcount;
    for (int i = blockIdx.x * blockDim.x + threadIdx.x; i < cnt;
         i += gridDim.x * blockDim.x) {
        int row = rlist[i];
        idx_out[row] = (int)(rpart[row] & 0xffffffffull);
    }
}

// ---------------------------------------------------------------------------
// Kernel 5: gather + loss partial + transposed write (unchanged).
// ---------------------------------------------------------------------------
__global__ void out_kernel(const float* __restrict__ z,
                           const float* __restrict__ emb,
                           const int* __restrict__ idx,
                           float* __restrict__ out,
                           float* __restrict__ losspart) {
    __shared__ float zq[64 * 129];
    __shared__ int ids[64];
    __shared__ float redl[4];

    const int bid = blockIdx.x;
    const int b = bid >> 6;
    const int h = bid & 63;
    const int rowbase = bid * 64;
    const int t = threadIdx.x;

    if (t < 64) ids[t] = idx[rowbase + t];
    __syncthreads();

    const int d = t & 127;
    const int w0 = t >> 7;
    float lsum = 0.f;
#pragma unroll
    for (int wq = 0; wq < 32; wq++) {
        int w = w0 + 2 * wq;
        float e = emb[(size_t)ids[w] * ND + d];
        float zv = z[((size_t)(rowbase + w)) * ND + d];
        float df = e - zv;
        lsum = fmaf(df, df, lsum);
        zq[w * 129 + d] = e;
    }
#pragma unroll
    for (int off = 32; off > 0; off >>= 1) lsum += __shfl_down(lsum, off, 64);
    if ((t & 63) == 0) redl[t >> 6] = lsum;
    __syncthreads();
    if (t == 0) losspart[bid] = redl[0] + redl[1] + redl[2] + redl[3];

    const int w = t & 63;
    const int dq = t >> 6;
#pragma unroll
    for (int dd0 = 0; dd0 < 32; dd0++) {
        int dd = dq + 4 * dd0;
        out[(((size_t)b * ND + dd) * NH + h) * NW + w] = zq[w * 129 + dd];
    }
}

// ---------------------------------------------------------------------------
// Kernel 6: final loss reduce
// ---------------------------------------------------------------------------
__global__ void loss_kernel(const float* __restrict__ losspart,
                            float* __restrict__ out) {
    __shared__ float redl[4];
    const int t = threadIdx.x;
    float s = 0.f;
#pragma unroll
    for (int i = 0; i < 4; i++) s += losspart[t + 256 * i];
#pragma unroll
    for (int off = 32; off > 0; off >>= 1) s += __shfl_down(s, off, 64);
    if ((t & 63) == 0) redl[t >> 6] = s;
    __syncthreads();
    if (t == 0) {
        float total = redl[0] + redl[1] + redl[2] + redl[3];
        out[OUT_ELEMS] = 1.25f * total / (float)OUT_ELEMS;
    }
}

// ---------------------------------------------------------------------------
extern "C" void kernel_launch(void* const* d_in, const int* in_sizes, int n_in,
                              void* d_out, int out_size, void* d_ws, size_t ws_size,
                              hipStream_t stream) {
    const float* z = (const float*)d_in[0];      // [16,64,64,128] fp32
    const float* emb = (const float*)d_in[1];    // [4096,128] fp32
    float* out = (float*)d_out;                  // 8388608 + 1 fp32

    char* ws = (char*)d_ws;
    int* ws_idx = (int*)ws;                                         // 256 KB
    float* ws_enorm = (float*)(ws + (256 << 10));                   // 16 KB
    float* ws_losspart = (float*)(ws + (272 << 10));                // 4 KB
    int* ws_rcount = (int*)(ws + (276 << 10));                      // 1 KB
    int* ws_rlist = (int*)(ws + (277 << 10));                       // 256 KB
    unsigned short* ws_eh = (unsigned short*)(ws + (533 << 10));    // 1 MB
    unsigned long long* ws_rpart = (unsigned long long*)(ws + (1557 << 10)); // 512 KB

    hipMemsetAsync(ws_rcount, 0, sizeof(int), stream);
    emb_prep_kernel<<<NK / 4, 256, 0, stream>>>(emb, ws_enorm, ws_eh);
    mfma_argmin_kernel<<<NROWS / 64, 256, 0, stream>>>(z, ws_eh, ws_enorm,
                                                       ws_idx, ws_rcount,
                                                       ws_rlist, ws_rpart);
    rescue_kernel<<<2048, 256, 0, stream>>>(z, emb, ws_enorm, ws_rcount,
                                            ws_rlist, ws_rpart);
    rescue_fin_kernel<<<64, 256, 0, stream>>>(ws_rcount, ws_rlist, ws_rpart,
                                              ws_idx);
    out_kernel<<<NB * NH, 256, 0, stream>>>(z, emb, ws_idx, out, ws_losspart);
    loss_kernel<<<1, 256, 0, stream>>>(ws_losspart, out);
}